// Round 1
// 193.970 us; speedup vs baseline: 4.6430x; 4.6430x over previous
//
#include <hip/hip_runtime.h>
#include <math.h>

// TSC (order-3) particle-to-mesh deposition.
//
// Fast path (C==8, n%4==0, n<=512): counting-sort atoms into 2x2xfull-z
// columns, then one block per column accumulates its tile in LDS (LDS
// atomics) and streams it to the planar output exactly once. No global
// atomics, no grid memset, no transpose.
//
// Fallbacks: previous interleaved-atomic two-phase (C==8), then generic
// planar-atomic kernel.

#define TX 2
#define TY 2

// TSC weight for axis offset o in {-1,0,+1} at fractional distance d in [-0.5,0.5]:
//   w(-1) = 0.5*(0.5-d)^2 ; w(0) = 0.75-d^2 ; w(+1) = 0.5*(0.5+d)^2
__device__ __forceinline__ float tsc_w(int o, float d) {
    float t = 0.5f + (float)o * d;
    return (o == 0) ? (0.75f - d * d) : (0.5f * t * t);
}

__device__ __forceinline__ float inv_spacing(const float* __restrict__ cell, int n) {
    float tr = cell[0] + cell[4] + cell[8];
    return (3.0f * (float)n) / tr;
}

// ---------------- binning (bins = TXxTY x full-z columns) ----------------

__global__ __launch_bounds__(256) void hist_bins(
    const float* __restrict__ pos, const float* __restrict__ cell,
    int* __restrict__ counts, int N, int n, int nby)
{
    int i = blockIdx.x * blockDim.x + threadIdx.x;
    if (i >= N) return;
    float inv_sp = inv_spacing(cell, n);
    float px = pos[3 * i + 0] * inv_sp;
    float py = pos[3 * i + 1] * inv_sp;
    int cx = (int)rintf(px); if (cx >= n) cx -= n;
    int cy = (int)rintf(py); if (cy >= n) cy -= n;
    int bin = (cx / TX) * nby + (cy / TY);
    atomicAdd(&counts[bin], 1);
}

// One block. offsets[nb+1] exclusive prefix; cursors = copy of offsets.
__global__ __launch_bounds__(256) void scan_bins(
    const int* __restrict__ counts, int* __restrict__ offsets,
    int* __restrict__ cursors, int nb)
{
    __shared__ int partial[256];
    int tid = threadIdx.x;
    int per = (nb + 255) / 256;
    int lo = tid * per; if (lo > nb) lo = nb;
    int hi = lo + per;  if (hi > nb) hi = nb;
    int s = 0;
    for (int i = lo; i < hi; ++i) s += counts[i];
    partial[tid] = s;
    __syncthreads();
    for (int off = 1; off < 256; off <<= 1) {
        int v = (tid >= off) ? partial[tid - off] : 0;
        __syncthreads();
        partial[tid] += v;
        __syncthreads();
    }
    int run = partial[tid] - s;  // exclusive prefix of this thread's chunk
    for (int i = lo; i < hi; ++i) {
        offsets[i] = run; cursors[i] = run; run += counts[i];
    }
    if (tid == 255) offsets[nb] = run;  // == N
}

__global__ __launch_bounds__(256) void scatter_bins(
    const float* __restrict__ pos, const float* __restrict__ cell,
    int* __restrict__ cursors, int* __restrict__ sidx, int N, int n, int nby)
{
    int i = blockIdx.x * blockDim.x + threadIdx.x;
    if (i >= N) return;
    float inv_sp = inv_spacing(cell, n);
    float px = pos[3 * i + 0] * inv_sp;
    float py = pos[3 * i + 1] * inv_sp;
    int cx = (int)rintf(px); if (cx >= n) cx -= n;
    int cy = (int)rintf(py); if (cy >= n) cy -= n;
    int bin = (cx / TX) * nby + (cy / TY);
    int p = atomicAdd(&cursors[bin], 1);
    sidx[p] = i;
}

// ---------------- tiled deposit: one block per column ----------------
// LDS layout: lds[(ch*TX*TY + lx*TY + ly) * n + lz]  (8*TX*TY runs of n floats)

__global__ __launch_bounds__(256) void deposit_tiled(
    const float* __restrict__ pos, const float* __restrict__ cell,
    const float* __restrict__ emb, const int* __restrict__ offsets,
    const int* __restrict__ sidx, float* __restrict__ out,
    int n, int nbx, int nby)
{
    extern __shared__ float lds[];
    const int tid = threadIdx.x;
    const int b = blockIdx.x;
    const int bx = b / nby, by = b - bx * nby;
    const int x0 = bx * TX, y0 = by * TY;
    const int plane = TX * TY * n;       // floats per channel
    const int sz = 8 * plane;            // total LDS floats

    for (int i = tid; i < sz; i += 256) lds[i] = 0.0f;

    __shared__ int s_start[9], s_cnt[9];
    if (tid < 9) {
        int dxb = tid / 3 - 1, dyb = tid % 3 - 1;
        int nx = bx + dxb; if (nx < 0) nx += nbx; else if (nx >= nbx) nx -= nbx;
        int ny = by + dyb; if (ny < 0) ny += nby; else if (ny >= nby) ny -= nby;
        int bb = nx * nby + ny;
        int st = offsets[bb];
        s_start[tid] = st;
        s_cnt[tid]   = offsets[bb + 1] - st;
    }
    __syncthreads();

    int pref[10];
    {
        int t = 0;
        #pragma unroll
        for (int j = 0; j < 9; ++j) { pref[j] = t; t += s_cnt[j]; }
        pref[9] = t;
    }
    const int tot = pref[9];
    const float inv_sp = inv_spacing(cell, n);
    const int half = n >> 1;

    for (int w = tid; w < tot; w += 256) {
        int j = 0;
        #pragma unroll
        for (int k = 1; k < 9; ++k) j += (w >= pref[k]);
        int ai = sidx[s_start[j] + (w - pref[j])];

        float px = pos[3 * ai + 0] * inv_sp;
        float py = pos[3 * ai + 1] * inv_sp;
        float pz = pos[3 * ai + 2] * inv_sp;
        int cx = (int)rintf(px); float dx = px - (float)cx;
        int cy = (int)rintf(py); float dy = py - (float)cy;
        int cz = (int)rintf(pz); float dz = pz - (float)cz;
        if (cx >= n) cx -= n;
        if (cy >= n) cy -= n;
        if (cz >= n) cz -= n;

        int rx = cx - x0; if (rx > half) rx -= n; else if (rx < -half) rx += n;
        int ry = cy - y0; if (ry > half) ry -= n; else if (ry < -half) ry += n;
        if (rx < -1 || rx > TX || ry < -1 || ry > TY) continue;

        float wzs[3] = { tsc_w(-1, dz), tsc_w(0, dz), tsc_w(1, dz) };
        int lz0 = cz - 1; if (lz0 < 0) lz0 += n;
        int lz2 = cz + 1; if (lz2 >= n) lz2 -= n;
        int lzs[3] = { lz0, cz, lz2 };

        const float4* e4 = (const float4*)(emb + (size_t)ai * 8);
        float4 e0 = e4[0], e1 = e4[1];

        #pragma unroll
        for (int lx = 0; lx < TX; ++lx) {
            int ox = lx - rx;
            if (ox < -1 || ox > 1) continue;
            float wxv = tsc_w(ox, dx);
            #pragma unroll
            for (int ly = 0; ly < TY; ++ly) {
                int oy = ly - ry;
                if (oy < -1 || oy > 1) continue;
                float wv = wxv * tsc_w(oy, dy);
                int base = (lx * TY + ly) * n;
                #pragma unroll
                for (int q = 0; q < 3; ++q) {
                    float wt = wv * wzs[q];
                    float* p = lds + base + lzs[q];
                    atomicAdd(p + 0 * plane, wt * e0.x);
                    atomicAdd(p + 1 * plane, wt * e0.y);
                    atomicAdd(p + 2 * plane, wt * e0.z);
                    atomicAdd(p + 3 * plane, wt * e0.w);
                    atomicAdd(p + 4 * plane, wt * e1.x);
                    atomicAdd(p + 5 * plane, wt * e1.y);
                    atomicAdd(p + 6 * plane, wt * e1.z);
                    atomicAdd(p + 7 * plane, wt * e1.w);
                }
            }
        }
    }
    __syncthreads();

    // Stream tile to planar out[ch][x][y][z]; run r = ch*4+lxy is n contiguous
    // floats, and (ch,lx) pairs give 2*n contiguous floats -> coalesced float4.
    const int n3 = n * n * n;
    const int nq = n >> 2;
    const int nf4 = sz >> 2;
    for (int i = tid; i < nf4; i += 256) {
        int r = i / nq; int q = i - r * nq;
        int ch = r >> 2; int lxy = r & 3; int lx = lxy >> 1; int ly = lxy & 1;
        float4 v = *(const float4*)(lds + (size_t)r * n + 4 * q);
        size_t off = (size_t)ch * n3 + ((size_t)(x0 + lx) * n + (y0 + ly)) * n + 4 * q;
        *(float4*)(out + off) = v;
    }
}

// ---------------- fallback 1: interleaved atomics + transpose ----------------

__global__ __launch_bounds__(256) void deposit_tsc8_ilv(
    const float* __restrict__ pos,
    const float* __restrict__ cell,
    const float* __restrict__ emb,
    float* __restrict__ ws,
    int total, int n)
{
    int t = blockIdx.x * blockDim.x + threadIdx.x;
    if (t >= total) return;
    int atom = t / 27;
    int c    = t - atom * 27;
    int a    = c / 9;
    int rem  = c - a * 9;
    int b    = rem / 3;
    int cc   = rem - b * 3;

    float inv_sp = inv_spacing(cell, n);

    float px = pos[3 * atom + 0] * inv_sp;
    float py = pos[3 * atom + 1] * inv_sp;
    float pz = pos[3 * atom + 2] * inv_sp;

    int cx = (int)rintf(px);  float dx = px - (float)cx;
    int cy = (int)rintf(py);  float dy = py - (float)cy;
    int cz = (int)rintf(pz);  float dz = pz - (float)cz;

    float w = tsc_w(a - 1, dx) * tsc_w(b - 1, dy) * tsc_w(cc - 1, dz);

    int x = cx - 1 + a;  if (x < 0) x += n; else if (x >= n) x -= n;
    int y = cy - 1 + b;  if (y < 0) y += n; else if (y >= n) y -= n;
    int z = cz - 1 + cc; if (z < 0) z += n; else if (z >= n) z -= n;

    const float4* e4 = (const float4*)(emb + (size_t)atom * 8);
    float4 e0 = e4[0], e1 = e4[1];

    float* p = ws + ((size_t)((x * n + y) * n + z)) * 8;
    atomicAdd(p + 0, w * e0.x);
    atomicAdd(p + 1, w * e0.y);
    atomicAdd(p + 2, w * e0.z);
    atomicAdd(p + 3, w * e0.w);
    atomicAdd(p + 4, w * e1.x);
    atomicAdd(p + 5, w * e1.y);
    atomicAdd(p + 6, w * e1.z);
    atomicAdd(p + 7, w * e1.w);
}

__global__ __launch_bounds__(256) void transpose_ilv8(
    const float* __restrict__ ws, float* __restrict__ out, int n3)
{
    int t = blockIdx.x * blockDim.x + threadIdx.x;
    int g0 = t * 4;
    if (g0 >= n3) return;
    const float4* w4 = (const float4*)(ws + (size_t)g0 * 8);
    float4 r0 = w4[0], r1 = w4[1];
    float4 r2 = w4[2], r3 = w4[3];
    float4 r4 = w4[4], r5 = w4[5];
    float4 r6 = w4[6], r7 = w4[7];

    *(float4*)(out + (size_t)0 * n3 + g0) = make_float4(r0.x, r2.x, r4.x, r6.x);
    *(float4*)(out + (size_t)1 * n3 + g0) = make_float4(r0.y, r2.y, r4.y, r6.y);
    *(float4*)(out + (size_t)2 * n3 + g0) = make_float4(r0.z, r2.z, r4.z, r6.z);
    *(float4*)(out + (size_t)3 * n3 + g0) = make_float4(r0.w, r2.w, r4.w, r6.w);
    *(float4*)(out + (size_t)4 * n3 + g0) = make_float4(r1.x, r3.x, r5.x, r7.x);
    *(float4*)(out + (size_t)5 * n3 + g0) = make_float4(r1.y, r3.y, r5.y, r7.y);
    *(float4*)(out + (size_t)6 * n3 + g0) = make_float4(r1.z, r3.z, r5.z, r7.z);
    *(float4*)(out + (size_t)7 * n3 + g0) = make_float4(r1.w, r3.w, r5.w, r7.w);
}

// ---------------- fallback 2: generic planar atomics ----------------

__global__ __launch_bounds__(256) void deposit_tsc_gen(
    const float* __restrict__ pos,
    const float* __restrict__ cell,
    const float* __restrict__ emb,
    float* __restrict__ out,
    int N, int n, int C)
{
    int i = blockIdx.x * blockDim.x + threadIdx.x;
    if (i >= N) return;

    float inv_sp = inv_spacing(cell, n);

    float p[3], d[3];
    int c0[3];
    #pragma unroll
    for (int k = 0; k < 3; ++k) {
        p[k] = pos[3 * i + k] * inv_sp;
        c0[k] = (int)rintf(p[k]);
        d[k] = p[k] - (float)c0[k];
    }
    float w[3][3];
    #pragma unroll
    for (int k = 0; k < 3; ++k) {
        float dd = d[k], d2 = dd * dd;
        w[k][0] = 0.125f * (1.0f - 4.0f * dd + 4.0f * d2);
        w[k][1] = 0.25f  * (3.0f - 4.0f * d2);
        w[k][2] = 0.125f * (1.0f + 4.0f * dd + 4.0f * d2);
    }
    int W[3][3];
    #pragma unroll
    for (int k = 0; k < 3; ++k) {
        #pragma unroll
        for (int a = 0; a < 3; ++a) {
            int v = c0[k] - 1 + a; if (v < 0) v += n; else if (v >= n) v -= n;
            W[k][a] = v;
        }
    }
    int n3 = n * n * n;
    for (int a = 0; a < 3; ++a)
        for (int b = 0; b < 3; ++b)
            for (int cc = 0; cc < 3; ++cc) {
                float wt = w[0][a] * w[1][b] * w[2][cc];
                int g = (W[0][a] * n + W[1][b]) * n + W[2][cc];
                for (int ch = 0; ch < C; ++ch)
                    atomicAdd(out + (size_t)ch * n3 + g, wt * emb[(size_t)i * C + ch]);
            }
}

extern "C" void kernel_launch(void* const* d_in, const int* in_sizes, int n_in,
                              void* d_out, int out_size, void* d_ws, size_t ws_size,
                              hipStream_t stream) {
    const float* pos  = (const float*)d_in[0];
    const float* cell = (const float*)d_in[1];
    const float* emb  = (const float*)d_in[2];
    float* out = (float*)d_out;
    float* ws  = (float*)d_ws;

    int N = in_sizes[0] / 3;
    int C = in_sizes[2] / N;
    long long n3l = (long long)out_size / C;
    int n = (int)llroundf(cbrtf((float)n3l));
    int n3 = (int)n3l;

    int block = 256;

    // ---- tiled fast path ----
    int nbx = n / TX, nby = n / TY, nb = nbx * nby;
    size_t lds_bytes  = (size_t)8 * TX * TY * n * sizeof(float);
    size_t ints_need  = (size_t)(nb + (nb + 1) + nb + N) * sizeof(int);
    bool tiled_ok = (C == 8) && (n % 4 == 0) && (n % TX == 0) && (n % TY == 0)
                    && nbx >= 3 && nby >= 3
                    && lds_bytes <= 64 * 1024
                    && ws_size >= ints_need
                    && ((long long)n * n * n == n3l);

    if (tiled_ok) {
        int* counts  = (int*)d_ws;
        int* offsets = counts + nb;        // nb+1 entries
        int* cursors = offsets + nb + 1;
        int* sidx    = cursors + nb;

        hipMemsetAsync(counts, 0, (size_t)nb * sizeof(int), stream);
        hist_bins<<<(N + block - 1) / block, block, 0, stream>>>(
            pos, cell, counts, N, n, nby);
        scan_bins<<<1, block, 0, stream>>>(counts, offsets, cursors, nb);
        scatter_bins<<<(N + block - 1) / block, block, 0, stream>>>(
            pos, cell, cursors, sidx, N, n, nby);
        deposit_tiled<<<nb, block, lds_bytes, stream>>>(
            pos, cell, emb, offsets, sidx, out, n, nbx, nby);
        return;
    }

    // ---- fallback paths ----
    size_t need = (size_t)out_size * sizeof(float);
    if (C == 8 && ws_size >= need && (n3 % 4) == 0) {
        hipMemsetAsync(d_ws, 0, need, stream);
        int total = N * 27;
        deposit_tsc8_ilv<<<(total + block - 1) / block, block, 0, stream>>>(
            pos, cell, emb, ws, total, n);
        int tthreads = n3 / 4;
        transpose_ilv8<<<(tthreads + block - 1) / block, block, 0, stream>>>(
            ws, out, n3);
    } else {
        hipMemsetAsync(d_out, 0, (size_t)out_size * sizeof(float), stream);
        int grid = (N + block - 1) / block;
        deposit_tsc_gen<<<grid, block, 0, stream>>>(pos, cell, emb, out, N, n, C);
    }
}